// Round 4
// baseline (73.008 us; speedup 1.0000x reference)
//
#include <hip/hip_runtime.h>

namespace {

constexpr int   kC    = 80;
constexpr int   kD    = 8525;
constexpr int   kB    = 64;
constexpr float kEps  = 1e-6f;
constexpr int   kOC   = 85;                 // outs channels
constexpr int   kGC   = 88;                 // gres channels
constexpr int   kBlk  = 256;
constexpr int   kPB   = kD * kOC;           // floats of outs per batch item
constexpr int   kSpb  = 32;                 // slices (blocks) per batch item
constexpr int   kRPS  = (kD + kSpb - 1) / kSpb;  // 267 rows per slice
constexpr int   kNT   = kB * kSpb;          // 2048 blocks

__device__ __forceinline__ float wave_reduce(float v) {
#pragma unroll
  for (int o = 32; o > 0; o >>= 1) v += __shfl_down(v, o, 64);
  return v;
}

__device__ __forceinline__ float fast_rcp(float x) {
  return __builtin_amdgcn_rcpf(x);
}

// raw neg-loss term: p^2 * log(1-p+eps), p = sigmoid(x)
__device__ __forceinline__ float lneg_raw(float x) {
  const float p = fast_rcp(1.0f + __expf(-x));
  return p * p * __logf(1.0f - p + kEps);
}

__global__ __launch_bounds__(kBlk, 8) void floss_fused(
    const float* __restrict__ outs, const float* __restrict__ gres,
    const float* __restrict__ grids, const int* __restrict__ nums_pos,
    float* __restrict__ partials) {
  const int bid = blockIdx.x;          // 0..2047
  const int tid = threadIdx.x;
  const int b   = bid >> 5;
  const int sb  = bid & 31;
  const int r0  = sb * kRPS;
  const int r1  = (r0 + kRPS < kD) ? r0 + kRPS : kD;
  const int nrows = r1 - r0;
  const float scale = fast_rcp(64.0f * (float)nums_pos[b]);

  __shared__ float s_tail[kRPS * 5];    // outs channels 80..84 per slice row
  __shared__ float s_grids[kRPS * 2];
  __shared__ float sm[3][kBlk / 64];

  for (int i = tid; i < 2 * nrows; i += kBlk) s_grids[i] = grids[2 * r0 + i];

  float pm = 0.f, pr = 0.f, pn = 0.f;

  // ---------- phase A: stream outs, lneg on cls channels, stash tails -----
  {
    const int sliceStart = b * kPB + r0 * kOC;
    const int gB = sliceStart + nrows * kOC;
    const int gv = (sliceStart + 3) & ~3;       // first float4-aligned idx
    const int nvec = (gB - gv) >> 2;
    const int gvend = gv + (nvec << 2);
    float lacc = 0.f;
    // head scalars: off = 0..2 -> always cls channels
    if (tid < gv - sliceStart) lacc += lneg_raw(outs[sliceStart + tid]);
    // tail scalars
    if (tid < gB - gvend) {
      const unsigned off = (unsigned)(gvend - sliceStart) + tid;
      const float x = outs[gvend + tid];
      const unsigned rl = off / 85u;
      const unsigned c  = off - 85u * rl;
      if (c < 80u) lacc += lneg_raw(x);
      else         s_tail[rl * 5 + (c - 80u)] = x;
    }
    for (int g = gv + 4 * tid; g < gvend; g += 4 * kBlk) {
      const float4 xv = *(const float4*)(outs + g);
      const unsigned off = (unsigned)(g - sliceStart);
      const unsigned rl = off / 85u;
      const unsigned c  = off - 85u * rl;
      const float xs[4] = {xv.x, xv.y, xv.z, xv.w};
#pragma unroll
      for (int k2 = 0; k2 < 4; ++k2) {
        unsigned ck = c + k2, rk = rl;
        if (ck >= 85u) { ck -= 85u; rk += 1u; }
        if (ck < 80u) lacc += lneg_raw(xs[k2]);
        else          s_tail[rk * 5 + (ck - 80u)] = xs[k2];
      }
    }
    pm += -0.75f * scale * lacc;
  }
  __syncthreads();

  // ---------- phase B: per-row terms, wave-parallel pos handling ----------
  const int w    = tid >> 6;
  const int lane = tid & 63;
  for (int k = 0; k < 2; ++k) {
    const int rl = k * kBlk + tid;            // slice-relative row
    const bool valid = rl < nrows;
    float4 t0 = make_float4(0.f, 0.f, 0.f, 0.f), t1 = t0;
    bool pos = false;
    if (valid) {
      const size_t gb = (size_t)(b * kD + r0 + rl) * kGC;
      t0 = *(const float4*)(gres + gb + 80);  // gcenter, l, t, r
      t1 = *(const float4*)(gres + gb + 84);  // b, mpp, mpos, 0
      if (t1.y == 1.0f) {                     // conf BCE
        const float pc = fast_rcp(1.0f + __expf(-s_tail[rl * 5]));
        pm += -5.0f * __logf(pc + kEps) * scale;
      }
      pos = (t1.z == 1.0f);
      if (pos) pn += 1.f;
    }
    unsigned long long mask = __ballot(pos);
    while (mask) {
      const int j = (int)(__ffsll((unsigned long long)mask) - 1);
      mask &= mask - 1;
      const int prl = k * kBlk + (w << 6) + j;   // pos row, slice-relative
      const float gcen = __shfl(t0.x, j);
      const float g0   = __shfl(t0.y, j);
      const float g1   = __shfl(t0.z, j);
      const float g2   = __shfl(t0.w, j);
      const float g3   = __shfl(t1.x, j);
      const size_t gb2 = (size_t)(b * kD + r0 + prl) * kGC;
      const float gv1 = gres[gb2 + lane];                         // c 0..63
      const float gv2 = (lane < 16) ? gres[gb2 + 64 + lane] : 0.f; // c 64..79
      const unsigned long long m1 = __ballot(gv1 == 1.0f);
      const unsigned long long m2 = __ballot((lane < 16) && gv2 == 1.0f);
      if ((m1 | m2) == 0ull) continue;
      const int lab = m1 ? (int)(__ffsll(m1) - 1) : 64 + (int)(__ffsll(m2) - 1);
      if (lane == 0) {
        // correction at label channel: + l_pos - l_neg
        const size_t ob = (size_t)(b * kD + r0 + prl) * kOC;
        const float x  = outs[ob + lab];
        const float p  = fast_rcp(1.0f + __expf(-x));
        const float om = 1.0f - p;
        const float lp = -0.25f * om * om * __logf(p + kEps);
        const float ln = -0.75f * p * p * __logf(om + kEps);
        pm += (lp - ln) * scale;
        // GIoU regression
        const float x81 = s_tail[prl * 5 + 1], x82 = s_tail[prl * 5 + 2];
        const float x83 = s_tail[prl * 5 + 3], x84 = s_tail[prl * 5 + 4];
        const float gx = s_grids[2 * prl], gy = s_grids[2 * prl + 1];
        const float p0 = gx - x81, p1 = gy - x82;
        const float p2 = gx + x83, p3 = gy + x84;
        const float iw = fmaxf(fminf(p2, g2) - fmaxf(p0, g0), 0.f);
        const float ih = fmaxf(fminf(p3, g3) - fmaxf(p1, g1), 0.f);
        const float inter = iw * ih;
        const float ap = fmaxf(p2 - p0, 0.f) * fmaxf(p3 - p1, 0.f);
        const float ag = fmaxf(g2 - g0, 0.f) * fmaxf(g3 - g1, 0.f);
        const float un = ap + ag - inter;
        const float iou = inter * fast_rcp(un + kEps);
        const float ca = (fmaxf(p2, g2) - fminf(p0, g0)) *
                         (fmaxf(p3, g3) - fminf(p1, g1));
        const float giou = iou - (ca - un) * fast_rcp(ca + kEps);
        pr += (1.0f - giou) * gcen;
      }
    }
  }

  // ---------- block reduction + partial write -----------------------------
  const float vm = wave_reduce(pm);
  const float vr = wave_reduce(pr);
  const float vn = wave_reduce(pn);
  if (lane == 0) { sm[0][w] = vm; sm[1][w] = vr; sm[2][w] = vn; }
  __syncthreads();
  if (tid == 0) {
    float m = 0.f, r = 0.f, n = 0.f;
#pragma unroll
    for (int j = 0; j < kBlk / 64; ++j) { m += sm[0][j]; r += sm[1][j]; n += sm[2][j]; }
    partials[bid * 3 + 0] = m;
    partials[bid * 3 + 1] = r;
    partials[bid * 3 + 2] = n;
  }
}

__global__ __launch_bounds__(kBlk) void floss_final(
    const float* __restrict__ partials, float* __restrict__ out) {
  float m = 0.f, r = 0.f, n = 0.f;
  for (int i = threadIdx.x; i < kNT; i += kBlk) {
    m += partials[i * 3 + 0];
    r += partials[i * 3 + 1];
    n += partials[i * 3 + 2];
  }
  __shared__ float sm[3][kBlk / 64];
  m = wave_reduce(m); r = wave_reduce(r); n = wave_reduce(n);
  const int lane = threadIdx.x & 63;
  const int w    = threadIdx.x >> 6;
  if (lane == 0) { sm[0][w] = m; sm[1][w] = r; sm[2][w] = n; }
  __syncthreads();
  if (threadIdx.x == 0) {
    float tm = 0.f, tr = 0.f, tn = 0.f;
#pragma unroll
    for (int j = 0; j < kBlk / 64; ++j) { tm += sm[0][j]; tr += sm[1][j]; tn += sm[2][j]; }
    out[0] = tm + 5.0f * tr / fmaxf(tn, 1.0f);
  }
}

}  // namespace

extern "C" void kernel_launch(void* const* d_in, const int* in_sizes, int n_in,
                              void* d_out, int out_size, void* d_ws, size_t ws_size,
                              hipStream_t stream) {
  const float* outs     = (const float*)d_in[0];
  const float* gres     = (const float*)d_in[1];
  const float* grids    = (const float*)d_in[2];
  const int*   nums_pos = (const int*)d_in[3];
  float* partials = (float*)d_ws;  // kNT * 3 * 4 B = 24,576 B

  floss_fused<<<kNT, kBlk, 0, stream>>>(outs, gres, grids, nums_pos, partials);
  floss_final<<<1, kBlk, 0, stream>>>(partials, (float*)d_out);
}

// Round 5
// 64.314 us; speedup vs baseline: 1.1352x; 1.1352x over previous
//
#include <hip/hip_runtime.h>

namespace {

constexpr int   kC    = 80;
constexpr int   kD    = 8525;
constexpr int   kB    = 64;
constexpr float kEps  = 1e-6f;
constexpr int   kOC   = 85;                 // outs channels
constexpr int   kGC   = 88;                 // gres channels
constexpr int   kBlk  = 256;
constexpr int   kPB   = kD * kOC;           // floats of outs per batch item
constexpr int   kSpb  = 32;                 // slices (blocks) per batch item
constexpr int   kRPS  = (kD + kSpb - 1) / kSpb;  // 267 rows per slice
constexpr int   kNT   = kB * kSpb;          // 2048 blocks
constexpr int   kQW   = 12;                 // queue words per pos row

__device__ __forceinline__ float wave_reduce(float v) {
#pragma unroll
  for (int o = 32; o > 0; o >>= 1) v += __shfl_down(v, o, 64);
  return v;
}

__device__ __forceinline__ float fast_rcp(float x) {
  return __builtin_amdgcn_rcpf(x);
}

// raw neg-loss term: p^2 * log(1-p+eps), p = sigmoid(x)
__device__ __forceinline__ float lneg_raw(float x) {
  const float p = fast_rcp(1.0f + __expf(-x));
  return p * p * __logf(1.0f - p + kEps);
}

__device__ __forceinline__ float lneg4(const float4 v) {
  return (lneg_raw(v.x) + lneg_raw(v.y)) + (lneg_raw(v.z) + lneg_raw(v.w));
}

__global__ __launch_bounds__(kBlk, 8) void floss_fused(
    const float* __restrict__ outs, const float* __restrict__ gres,
    const float* __restrict__ grids, const int* __restrict__ nums_pos,
    float* __restrict__ partials) {
  const int bid = blockIdx.x;          // 0..2047
  const int tid = threadIdx.x;
  const int b   = bid >> 5;
  const int sb  = bid & 31;
  const int r0  = sb * kRPS;
  const int r1  = (r0 + kRPS < kD) ? r0 + kRPS : kD;
  const int nrows = r1 - r0;
  const float scale = fast_rcp(64.0f * (float)nums_pos[b]);

  __shared__ float s_q[kRPS * kQW];    // pos-row queue
  __shared__ int   s_cnt;
  __shared__ float sm[3][kBlk / 64];
  if (tid == 0) s_cnt = 0;

  float pm = 0.f, pr = 0.f, pn = 0.f;

  // ---------- phase A: lean stream, lneg over ALL 85 channels, 4-deep MLP --
  {
    const int gA = b * kPB + r0 * kOC;
    const int gB = gA + nrows * kOC;
    const int gv = (gA + 3) & ~3;             // first float4-aligned idx
    const int nvec = (gB - gv) >> 2;
    const int gvend = gv + (nvec << 2);
    float a0 = 0.f, a1 = 0.f, a2 = 0.f, a3 = 0.f;
    if (tid < gv - gA)    a0 += lneg_raw(outs[gA + tid]);
    if (tid < gB - gvend) a1 += lneg_raw(outs[gvend + tid]);
    const float* pv = outs + gv;
    int v = tid;
    for (; v + 3 * kBlk < nvec; v += 4 * kBlk) {
      const float4 xa = *(const float4*)(pv + 4 * v);
      const float4 xb = *(const float4*)(pv + 4 * (v + kBlk));
      const float4 xc = *(const float4*)(pv + 4 * (v + 2 * kBlk));
      const float4 xd = *(const float4*)(pv + 4 * (v + 3 * kBlk));
      a0 += lneg4(xa);
      a1 += lneg4(xb);
      a2 += lneg4(xc);
      a3 += lneg4(xd);
    }
    for (; v < nvec; v += kBlk) a0 += lneg4(*(const float4*)(pv + 4 * v));
    pm += -0.75f * scale * ((a0 + a1) + (a2 + a3));
  }
  __syncthreads();  // s_cnt visible; phase A done

  // ---------- phase B stage 1: one row per lane ---------------------------
  for (int rl = tid; rl < nrows; rl += kBlk) {
    const int r   = r0 + rl;
    const int row = b * kD + r;
    const float* orow = outs + (size_t)row * kOC;
    const float x80 = orow[80], x81 = orow[81], x82 = orow[82],
                x83 = orow[83], x84 = orow[84];
    const size_t gb = (size_t)row * kGC;
    const float4 t0 = *(const float4*)(gres + gb + 80);  // gcen, l, t, r
    const float4 t1 = *(const float4*)(gres + gb + 84);  // b, mpp, mpos, 0
    // remove the 5 tail-channel lneg contributions phase A added
    const float t5 = ((lneg_raw(x80) + lneg_raw(x81)) +
                     (lneg_raw(x82) + lneg_raw(x83))) + lneg_raw(x84);
    pm += 0.75f * scale * t5;
    if (t1.y == 1.0f) {  // conf BCE
      const float pc = fast_rcp(1.0f + __expf(-x80));
      pm += -5.0f * __logf(pc + kEps) * scale;
    }
    if (t1.z == 1.0f) {  // pos row -> queue
      pn += 1.0f;
      const int slot = atomicAdd(&s_cnt, 1);
      float* q = s_q + slot * kQW;
      q[0]  = t0.x;                       // gcenter
      q[1]  = t0.y; q[2] = t0.z; q[3] = t0.w; q[4] = t1.x;  // g ltrb
      q[5]  = x81;  q[6] = x82;  q[7] = x83;  q[8] = x84;   // pred offsets
      q[9]  = grids[2 * r + 0];
      q[10] = grids[2 * r + 1];
      q[11] = __int_as_float(row);
    }
  }
  __syncthreads();

  // ---------- phase B stage 2: half-wave per queued pos row ---------------
  {
    const int nq = s_cnt;
    const int hh = tid >> 5;      // half-wave id 0..7
    const int h  = tid & 31;      // lane within half-wave
    for (int e = hh; e < nq; e += 8) {
      const float* q = s_q + e * kQW;
      const int row = __float_as_int(q[11]);
      int cand = -1;
      if (h < 20) {
        const float4 v = *(const float4*)(gres + (size_t)row * kGC + 4 * h);
        if (v.x == 1.0f) cand = 4 * h;
        if (v.y == 1.0f) cand = 4 * h + 1;
        if (v.z == 1.0f) cand = 4 * h + 2;
        if (v.w == 1.0f) cand = 4 * h + 3;
      }
#pragma unroll
      for (int m = 16; m > 0; m >>= 1) {
        const int o = __shfl_xor(cand, m, 32);
        cand = (o > cand) ? o : cand;
      }
      if (h == 0 && cand >= 0) {
        // correction at label channel: + l_pos - l_neg
        const float x  = outs[(size_t)row * kOC + cand];
        const float p  = fast_rcp(1.0f + __expf(-x));
        const float om = 1.0f - p;
        const float lp = -0.25f * om * om * __logf(p + kEps);
        const float ln = -0.75f * p * p * __logf(om + kEps);
        pm += (lp - ln) * scale;
        // GIoU regression
        const float gx = q[9], gy = q[10];
        const float p0 = gx - q[5], p1 = gy - q[6];
        const float p2 = gx + q[7], p3 = gy + q[8];
        const float g0 = q[1], g1 = q[2], g2 = q[3], g3 = q[4];
        const float iw = fmaxf(fminf(p2, g2) - fmaxf(p0, g0), 0.f);
        const float ih = fmaxf(fminf(p3, g3) - fmaxf(p1, g1), 0.f);
        const float inter = iw * ih;
        const float ap = fmaxf(p2 - p0, 0.f) * fmaxf(p3 - p1, 0.f);
        const float ag = fmaxf(g2 - g0, 0.f) * fmaxf(g3 - g1, 0.f);
        const float un = ap + ag - inter;
        const float iou = inter * fast_rcp(un + kEps);
        const float ca = (fmaxf(p2, g2) - fminf(p0, g0)) *
                         (fmaxf(p3, g3) - fminf(p1, g1));
        const float giou = iou - (ca - un) * fast_rcp(ca + kEps);
        pr += (1.0f - giou) * q[0];
      }
    }
  }

  // ---------- block reduction + partial write -----------------------------
  const float vm = wave_reduce(pm);
  const float vr = wave_reduce(pr);
  const float vn = wave_reduce(pn);
  const int lane = tid & 63;
  const int w    = tid >> 6;
  if (lane == 0) { sm[0][w] = vm; sm[1][w] = vr; sm[2][w] = vn; }
  __syncthreads();
  if (tid == 0) {
    float m = 0.f, r = 0.f, n = 0.f;
#pragma unroll
    for (int j = 0; j < kBlk / 64; ++j) { m += sm[0][j]; r += sm[1][j]; n += sm[2][j]; }
    partials[bid * 3 + 0] = m;
    partials[bid * 3 + 1] = r;
    partials[bid * 3 + 2] = n;
  }
}

__global__ __launch_bounds__(kBlk) void floss_final(
    const float* __restrict__ partials, float* __restrict__ out) {
  float m = 0.f, r = 0.f, n = 0.f;
  for (int i = threadIdx.x; i < kNT; i += kBlk) {
    m += partials[i * 3 + 0];
    r += partials[i * 3 + 1];
    n += partials[i * 3 + 2];
  }
  __shared__ float sm[3][kBlk / 64];
  m = wave_reduce(m); r = wave_reduce(r); n = wave_reduce(n);
  const int lane = threadIdx.x & 63;
  const int w    = threadIdx.x >> 6;
  if (lane == 0) { sm[0][w] = m; sm[1][w] = r; sm[2][w] = n; }
  __syncthreads();
  if (threadIdx.x == 0) {
    float tm = 0.f, tr = 0.f, tn = 0.f;
#pragma unroll
    for (int j = 0; j < kBlk / 64; ++j) { tm += sm[0][j]; tr += sm[1][j]; tn += sm[2][j]; }
    out[0] = tm + 5.0f * tr / fmaxf(tn, 1.0f);
  }
}

}  // namespace

extern "C" void kernel_launch(void* const* d_in, const int* in_sizes, int n_in,
                              void* d_out, int out_size, void* d_ws, size_t ws_size,
                              hipStream_t stream) {
  const float* outs     = (const float*)d_in[0];
  const float* gres     = (const float*)d_in[1];
  const float* grids    = (const float*)d_in[2];
  const int*   nums_pos = (const int*)d_in[3];
  float* partials = (float*)d_ws;  // kNT * 3 * 4 B = 24,576 B

  floss_fused<<<kNT, kBlk, 0, stream>>>(outs, gres, grids, nums_pos, partials);
  floss_final<<<1, kBlk, 0, stream>>>(partials, (float*)d_out);
}